// Round 5
// baseline (413.100 us; speedup 1.0000x reference)
//
#include <hip/hip_runtime.h>
#include <hip/hip_bf16.h>

// GCN: N=50000, E=800000, hidden 64, 5 convs (relu on first 4).
// f32 tensors, int32 edge_index, f32 d_out[N].  ws_size in [19.8, 26.0) MB.
// r22: dual-node ILP in the gather convs. r21 post-mortem: convs ~10x above their
// throughput floor (102MB/conv ~ 3-4us), occupancy pinned at 4 waves/SIMD by
// wreg[64], per-node chain ~2-3Kcy unpipelined (compiler can't pipeline across
// the node loop). Single mechanism: each wave-iteration gathers TWO consecutive
// nodes with a FUSED inner loop (2 bucket + 4 feat loads in flight vs 1+2) ->
// 2x memory parallelism per wave at ~+20 VGPR (fits under the 128 cap of
// launch_bounds(256,4)). Combine/transform sequential per node (short). Applied
// to k_gconv (x2) and k_gconv_z (now persistent). gconv1/k_out/CSR unchanged.
// Workspace (~19.0 MB): gA bf16[N*64] | gB bf16[N*64] | xt f32x4[N] | bucket u16[E]
//   | staging u32[E] | row_start i32[N+1] | dinv f32[N] | zg f32[N] | bktcnt i32[256]
//   | ticket i32 | bktbase i32[257] | bcur i32[256]

#define TPB 256
#define EPT 8                    // edges per thread in k_bktcnt / k_bin
#define CHUNK (TPB * EPT)        // 2048 edges per block
typedef __hip_bfloat16 bf16;
#define B2F __bfloat162float

__global__ void k_zero_b(int* __restrict__ bktcnt, int* __restrict__ ticket) {
    bktcnt[threadIdx.x] = 0;
    if (threadIdx.x == 0) *ticket = 0;
}

// Per-bucket (dst>>8) edge counts via LDS histogram; LAST block (ticket) also
// performs the 256-wide exclusive scan -> bktbase[257], bcur (fuses k_bktscan).
__global__ __launch_bounds__(TPB) void k_bktcnt(
    const int* __restrict__ dst, int* __restrict__ bktcnt, int* __restrict__ ticket,
    int* __restrict__ bktbase, int* __restrict__ bcur, int E, int n) {
    __shared__ int h[256];
    __shared__ int lastFlag;
    int tid = threadIdx.x;
    h[tid] = 0;
    __syncthreads();
    int e0 = blockIdx.x * CHUNK;
#pragma unroll
    for (int u = 0; u < EPT; ++u) {
        int e = e0 + u * TPB + tid;
        if (e < E) {
            int d = dst[e];
            if ((unsigned)d < (unsigned)n) atomicAdd(&h[d >> 8], 1);
        }
    }
    __syncthreads();
    if (h[tid]) atomicAdd(&bktcnt[tid], h[tid]);
    __threadfence();                               // counts visible before ticket
    __syncthreads();
    if (tid == 0) lastFlag = (atomicAdd(ticket, 1) == (int)gridDim.x - 1);
    __syncthreads();
    if (!lastFlag) return;                         // block-uniform exit
    // last block: coherent read of final counts, then scan (reuse h as buffer)
    int v = atomicAdd(&bktcnt[tid], 0);
    h[tid] = v;
    __syncthreads();
    for (int off = 1; off < 256; off <<= 1) {
        int u2 = (tid >= off) ? h[tid - off] : 0;
        __syncthreads();
        h[tid] += u2;
        __syncthreads();
    }
    int excl = h[tid] - v;
    bktbase[tid] = excl;
    bcur[tid] = excl;
    if (tid == 255) bktbase[256] = h[tid];
}

// Pass 1: bin edges by dst>>8 into staging (record = src | (dst&255)<<16).
__global__ __launch_bounds__(TPB) void k_bin(
    const int* __restrict__ src, const int* __restrict__ dst,
    int* __restrict__ bcur, unsigned* __restrict__ staging, int E, int n) {
    __shared__ int hcnt[256];
    __shared__ int hbase[256];
    int tid = threadIdx.x;
    int e0 = blockIdx.x * CHUNK;
    hcnt[tid] = 0;
    __syncthreads();

    int eb[EPT];
    unsigned rec[EPT];
#pragma unroll
    for (int u = 0; u < EPT; ++u) {
        int e = e0 + u * TPB + tid;
        eb[u] = -1;
        if (e < E) {
            int d = dst[e], s = src[e];
            if ((unsigned)d < (unsigned)n && (unsigned)s < (unsigned)n) {
                eb[u] = d >> 8;
                rec[u] = (unsigned)s | ((unsigned)(d & 255) << 16);
                atomicAdd(&hcnt[eb[u]], 1);
            }
        }
    }
    __syncthreads();
    int c = hcnt[tid];
    hbase[tid] = (c > 0) ? atomicAdd(&bcur[tid], c) : 0;
    hcnt[tid] = 0;
    __syncthreads();
#pragma unroll
    for (int u = 0; u < EPT; ++u) {
        if (eb[u] >= 0) {
            int r = atomicAdd(&hcnt[eb[u]], 1);
            int pos = hbase[eb[u]] + r;
            if ((unsigned)pos < (unsigned)E) staging[pos] = rec[u];  // replay-safe
        }
    }
}

// Pass 2: one block per bucket. Per-node histogram + prefix in LDS -> row_start,
// dinv, xt (=x*dinv), and record placement via LDS cursors.
__global__ __launch_bounds__(TPB) void k_unbin2(
    const unsigned* __restrict__ staging, const int* __restrict__ bktbase,
    const float* __restrict__ x, float4* __restrict__ xt,
    int* __restrict__ row_start, float* __restrict__ dinv,
    unsigned short* __restrict__ bucket, int E, int n) {
    __shared__ int cnt[256];
    __shared__ int scn[256];
    __shared__ int cur[256];
    int b = blockIdx.x, tid = threadIdx.x;
    int lo = bktbase[b], hi = bktbase[b + 1];
    lo = max(0, min(lo, E)); hi = max(lo, min(hi, E));

    cnt[tid] = 0;
    __syncthreads();
    for (int i = lo + tid; i < hi; i += TPB)
        atomicAdd(&cnt[(staging[i] >> 16) & 255], 1);
    __syncthreads();

    int v = cnt[tid];
    scn[tid] = v;
    __syncthreads();
    for (int off = 1; off < 256; off <<= 1) {
        int u = (tid >= off) ? scn[tid - off] : 0;
        __syncthreads();
        scn[tid] += u;
        __syncthreads();
    }
    int excl = scn[tid] - v;
    int base = min(lo + excl, E);
    cur[tid] = base;
    int d = (b << 8) + tid;
    if (d < n) {
        row_start[d] = base;
        float di = rsqrtf((float)v + 1.0f);    // +1 self-loop
        dinv[d] = di;
        float4 xv = ((const float4*)x)[d];     // x is f32[N][4], 16B aligned
        xv.x *= di; xv.y *= di; xv.z *= di; xv.w *= di;
        xt[d] = xv;                            // premultiplied raw features
        if (d == n - 1) row_start[n] = min(base + v, E);
    }
    __syncthreads();

    for (int i = lo + tid; i < hi; i += TPB) {
        unsigned r = staging[i];
        int t = (r >> 16) & 255;
        int pos = atomicAdd(&cur[t], 1);
        if ((unsigned)pos < (unsigned)E) bucket[pos] = (unsigned short)(r & 0xffffu);
    }
}

__device__ __forceinline__ void acc_oct(float* a, uint4 w) {
    a[0] += __uint_as_float(w.x << 16);
    a[1] += __uint_as_float(w.x & 0xffff0000u);
    a[2] += __uint_as_float(w.y << 16);
    a[3] += __uint_as_float(w.y & 0xffff0000u);
    a[4] += __uint_as_float(w.z << 16);
    a[5] += __uint_as_float(w.z & 0xffff0000u);
    a[6] += __uint_as_float(w.w << 16);
    a[7] += __uint_as_float(w.w & 0xffff0000u);
}

// Single-node chunk remainder (r17 shape): edges [kstart,cnt) of one 64-edge chunk.
__device__ __forceinline__ void agg_chunk(const bf16* __restrict__ g, int rec,
                                          int kstart, int cnt, float* __restrict__ a,
                                          int grp, int i, unsigned nm1) {
    int k = kstart;
    for (; k + 16 <= cnt; k += 16) {
        unsigned s0 = min((unsigned)__shfl(rec, k + grp), nm1);
        unsigned s1 = min((unsigned)__shfl(rec, k + 8 + grp), nm1);
        uint4 w0 = *(const uint4*)(g + (size_t)s0 * 64 + 8 * i);
        uint4 w1 = *(const uint4*)(g + (size_t)s1 * 64 + 8 * i);
        acc_oct(a, w0);
        acc_oct(a, w1);
    }
    for (; k < cnt; k += 8) {                              // tail, predicated
        int e = k + grp;
        unsigned s = min((unsigned)__shfl(rec, min(e, 63)), nm1);
        uint4 w = *(const uint4*)(g + (size_t)s * 64 + 8 * i);
        if (e < cnt) acc_oct(a, w);
    }
}

// Dual-node OCT gather: nodes A and B gathered with a FUSED inner loop — per
// chunk pair, 2 independent bucket loads then 4 independent oct feat loads in
// flight (vs 1+2 single-node) -> 2x memory parallelism on the latency-critical
// path. Remainders/odd chunks fall back to agg_chunk. All loop bounds wave-uniform.
__device__ __forceinline__ void agg_oct2(const bf16* __restrict__ g,
                                         const unsigned short* __restrict__ bucket,
                                         int k0a, int k1a, int da,
                                         int k0b, int k1b, int db, bool hasB,
                                         float* __restrict__ aA, float* __restrict__ aB,
                                         int lane, unsigned nm1, unsigned Em1) {
    int grp = lane >> 3, i = lane & 7;
#pragma unroll
    for (int m = 0; m < 8; ++m) { aA[m] = 0.f; aB[m] = 0.f; }
    if (grp == 0) {  // self terms (independent loads)
        uint4 wa = *(const uint4*)(g + (size_t)da * 64 + 8 * i);
        acc_oct(aA, wa);
        if (hasB) {
            uint4 wb = *(const uint4*)(g + (size_t)db * 64 + 8 * i);
            acc_oct(aB, wb);
        }
    }
    int bA = k0a, bB = k0b;
    while (bA < k1a && bB < k1b) {        // fused chunk pair (wave-uniform)
        int cA = min(64, k1a - bA), cB = min(64, k1b - bB);
        int recA = bucket[min((unsigned)(bA + lane), Em1)];
        int recB = bucket[min((unsigned)(bB + lane), Em1)];
        int cm = min(cA, cB);
        int k = 0;
        for (; k + 16 <= cm; k += 16) {   // 4 independent oct loads in flight
            unsigned s0a = min((unsigned)__shfl(recA, k + grp), nm1);
            unsigned s1a = min((unsigned)__shfl(recA, k + 8 + grp), nm1);
            unsigned s0b = min((unsigned)__shfl(recB, k + grp), nm1);
            unsigned s1b = min((unsigned)__shfl(recB, k + 8 + grp), nm1);
            uint4 w0a = *(const uint4*)(g + (size_t)s0a * 64 + 8 * i);
            uint4 w1a = *(const uint4*)(g + (size_t)s1a * 64 + 8 * i);
            uint4 w0b = *(const uint4*)(g + (size_t)s0b * 64 + 8 * i);
            uint4 w1b = *(const uint4*)(g + (size_t)s1b * 64 + 8 * i);
            acc_oct(aA, w0a);
            acc_oct(aA, w1a);
            acc_oct(aB, w0b);
            acc_oct(aB, w1b);
        }
        agg_chunk(g, recA, k, cA, aA, grp, i, nm1);   // A remainder of this chunk
        agg_chunk(g, recB, k, cB, aB, grp, i, nm1);   // B remainder of this chunk
        bA += 64; bB += 64;
    }
    for (; bA < k1a; bA += 64) {          // A-only leftover chunks
        int cA = min(64, k1a - bA);
        int recA = bucket[min((unsigned)(bA + lane), Em1)];
        agg_chunk(g, recA, 0, cA, aA, grp, i, nm1);
    }
    for (; bB < k1b; bB += 64) {          // B-only leftover chunks
        int cB = min(64, k1b - bB);
        int recB = bucket[min((unsigned)(bB + lane), Em1)];
        agg_chunk(g, recB, 0, cB, aB, grp, i, nm1);
    }
}

// Layer 1, aggregate-first (r21): agg4[d] = xt[d] + sum xt[s] (16B f32 rows).
// Lane-parallel gather, butterfly reduce, 4-fma W_in transform, relu; persistent
// tail with W_h0 column in 64 VGPRs. Unchanged from r21.
__global__ __launch_bounds__(TPB, 4) void k_gconv1(
    const float4* __restrict__ xt, const float* __restrict__ dinv,
    const int* __restrict__ row_start, const unsigned short* __restrict__ bucket,
    const float* __restrict__ W_in, const float* __restrict__ b_in,
    const float* __restrict__ Wh0, bf16* __restrict__ gOut, int n, int E) {
    __shared__ float sAct[4][64];
    int tid = threadIdx.x;
    int r = tid >> 6, j = tid & 63;
    unsigned nm1 = (unsigned)(n - 1);

    float wreg[64];
#pragma unroll
    for (int k = 0; k < 64; ++k) wreg[k] = Wh0[k * 64 + j];
    float win0 = W_in[0 * 64 + j], win1 = W_in[1 * 64 + j];
    float win2 = W_in[2 * 64 + j], win3 = W_in[3 * 64 + j];
    float bj = b_in[j];

    int nw = gridDim.x * 4;
    for (int d = blockIdx.x * 4 + r; d < n; d += nw) {      // wave-uniform loop
        float dd = dinv[d];
        int k0 = row_start[d], k1 = row_start[d + 1];
        k1 = min(k1, E); k0 = max(min(k0, k1), 0);

        float4 v = make_float4(0.f, 0.f, 0.f, 0.f);
        if (j == 0) v = xt[d];                              // self term
        for (int k = k0 + j; k < k1; k += 64) {
            unsigned s = min((unsigned)bucket[k], nm1);
            float4 t = xt[s];
            v.x += t.x; v.y += t.y; v.z += t.z; v.w += t.w;
        }
#pragma unroll
        for (int off = 1; off < 64; off <<= 1) {            // butterfly: all lanes
            v.x += __shfl_xor(v.x, off);
            v.y += __shfl_xor(v.y, off);
            v.z += __shfl_xor(v.z, off);
            v.w += __shfl_xor(v.w, off);
        }
        float dot = fmaf(v.x, win0, fmaf(v.y, win1, fmaf(v.z, win2, v.w * win3)));
        float act = fmaxf(fmaf(dd, dot, bj), 0.f);
        sAct[r][j] = act;                 // wave-local RAW -> lgkmcnt, no barrier

        float acc0 = 0.f, acc1 = 0.f, acc2 = 0.f, acc3 = 0.f;
        const float4* ap = (const float4*)&sAct[r][0];
#pragma unroll
        for (int k4 = 0; k4 < 16; ++k4) {
            float4 av = ap[k4];           // wave-uniform address -> broadcast b128
            acc0 = fmaf(av.x, wreg[4 * k4 + 0], acc0);
            acc1 = fmaf(av.y, wreg[4 * k4 + 1], acc1);
            acc2 = fmaf(av.z, wreg[4 * k4 + 2], acc2);
            acc3 = fmaf(av.w, wreg[4 * k4 + 3], acc3);
        }
        float acc = (acc0 + acc1) + (acc2 + acc3);
        gOut[(size_t)d * 64 + j] = __float2bfloat16(acc * dd);
    }
}

// Persistent fused middle layer, dual-node: each wave-iteration gathers nodes
// 2p and 2p+1 with the fused agg_oct2, then combines/transforms each via the
// padded LDS rows (in-order wave-local DS => no barriers, safe A-then-B reuse).
__global__ __launch_bounds__(TPB, 4) void k_gconv(
    const bf16* __restrict__ gIn, const float* __restrict__ dinv,
    const int* __restrict__ row_start, const unsigned short* __restrict__ bucket,
    const float* __restrict__ bias, const float* __restrict__ W,
    bf16* __restrict__ gOut, int n, int E) {
    __shared__ float sVp[4][8][68];      // 8704 B, padded
    int tid = threadIdx.x;
    int r = tid >> 6, j = tid & 63;
    int grp = j >> 3, i = j & 7;
    unsigned nm1 = (unsigned)(n - 1), Em1 = (unsigned)(E - 1);

    float wreg[64];
#pragma unroll
    for (int k = 0; k < 64; ++k) wreg[k] = W[k * 64 + j];   // coalesced per k
    float bj = bias[j];

    int nw = gridDim.x * 4;
    int npair = (n + 1) >> 1;
    for (int p = blockIdx.x * 4 + r; p < npair; p += nw) {  // wave-uniform loop
        int dA = 2 * p, dB = dA + 1;
        bool hasB = dB < n;
        float ddA = dinv[dA];
        int k0a = row_start[dA], k1a = row_start[dA + 1];
        k1a = min(k1a, E); k0a = max(min(k0a, k1a), 0);
        float ddB = 0.f;
        int k0b = 0, k1b = 0;
        if (hasB) {
            ddB = dinv[dB];
            k0b = row_start[dB]; k1b = row_start[dB + 1];
            k1b = min(k1b, E); k0b = max(min(k0b, k1b), 0);
        }

        float aA[8], aB[8];
        agg_oct2(gIn, bucket, k0a, k1a, dA, k0b, k1b, min(dB, n - 1), hasB,
                 aA, aB, j, nm1, Em1);

        // ---- node A: combine + transform ----
        float4* prow = (float4*)&sVp[r][grp][8 * i];
        prow[0] = make_float4(aA[0], aA[1], aA[2], aA[3]);
        prow[1] = make_float4(aA[4], aA[5], aA[6], aA[7]);
        float full = 0.f;
#pragma unroll
        for (int g = 0; g < 8; ++g) full += sVp[r][g][j];   // 2-way bank: free
        float act = fmaxf(fmaf(ddA, full, bj), 0.f);
        sVp[r][0][j] = act;               // reads above already issued (in-order)
        float acc0 = 0.f, acc1 = 0.f, acc2 = 0.f, acc3 = 0.f;
#pragma unroll
        for (int k4 = 0; k4 < 16; ++k4) {
            float4 av = *(const float4*)&sVp[r][0][4 * k4];   // broadcast b128
            acc0 = fmaf(av.x, wreg[4 * k4 + 0], acc0);
            acc1 = fmaf(av.y, wreg[4 * k4 + 1], acc1);
            acc2 = fmaf(av.z, wreg[4 * k4 + 2], acc2);
            acc3 = fmaf(av.w, wreg[4 * k4 + 3], acc3);
        }
        gOut[(size_t)dA * 64 + j] = __float2bfloat16(((acc0 + acc1) + (acc2 + acc3)) * ddA);

        // ---- node B: combine + transform (in-order DS makes row reuse safe) ----
        if (hasB) {
            prow[0] = make_float4(aB[0], aB[1], aB[2], aB[3]);
            prow[1] = make_float4(aB[4], aB[5], aB[6], aB[7]);
            float fullB = 0.f;
#pragma unroll
            for (int g = 0; g < 8; ++g) fullB += sVp[r][g][j];
            float actB = fmaxf(fmaf(ddB, fullB, bj), 0.f);
            sVp[r][0][j] = actB;
            float b0 = 0.f, b1 = 0.f, b2 = 0.f, b3 = 0.f;
#pragma unroll
            for (int k4 = 0; k4 < 16; ++k4) {
                float4 av = *(const float4*)&sVp[r][0][4 * k4];
                b0 = fmaf(av.x, wreg[4 * k4 + 0], b0);
                b1 = fmaf(av.y, wreg[4 * k4 + 1], b1);
                b2 = fmaf(av.z, wreg[4 * k4 + 2], b2);
                b3 = fmaf(av.w, wreg[4 * k4 + 3], b3);
            }
            gOut[(size_t)dB * 64 + j] = __float2bfloat16(((b0 + b1) + (b2 + b3)) * ddB);
        }
    }
}

// Last hidden conv fused with 64->1 matmul, persistent dual-node:
// zg[d] = (relu(dd*sum+b) . Wout) * dd.  Same gather as k_gconv; light tail.
__global__ __launch_bounds__(TPB, 4) void k_gconv_z(
    const bf16* __restrict__ gIn, const float* __restrict__ dinv,
    const int* __restrict__ row_start, const unsigned short* __restrict__ bucket,
    const float* __restrict__ bias, const float* __restrict__ Wout,
    float* __restrict__ zg, int n, int E) {
    __shared__ float sVp[4][8][68];
    int tid = threadIdx.x;
    int r = tid >> 6, j = tid & 63;
    int grp = j >> 3, i = j & 7;
    unsigned nm1 = (unsigned)(n - 1), Em1 = (unsigned)(E - 1);
    float bj = bias[j], wj = Wout[j];

    int nw = gridDim.x * 4;
    int npair = (n + 1) >> 1;
    for (int p = blockIdx.x * 4 + r; p < npair; p += nw) {  // wave-uniform loop
        int dA = 2 * p, dB = dA + 1;
        bool hasB = dB < n;
        float ddA = dinv[dA];
        int k0a = row_start[dA], k1a = row_start[dA + 1];
        k1a = min(k1a, E); k0a = max(min(k0a, k1a), 0);
        float ddB = 0.f;
        int k0b = 0, k1b = 0;
        if (hasB) {
            ddB = dinv[dB];
            k0b = row_start[dB]; k1b = row_start[dB + 1];
            k1b = min(k1b, E); k0b = max(min(k0b, k1b), 0);
        }

        float aA[8], aB[8];
        agg_oct2(gIn, bucket, k0a, k1a, dA, k0b, k1b, min(dB, n - 1), hasB,
                 aA, aB, j, nm1, Em1);

        float4* prow = (float4*)&sVp[r][grp][8 * i];
        prow[0] = make_float4(aA[0], aA[1], aA[2], aA[3]);
        prow[1] = make_float4(aA[4], aA[5], aA[6], aA[7]);
        float full = 0.f;
#pragma unroll
        for (int g = 0; g < 8; ++g) full += sVp[r][g][j];
        float pA = fmaxf(fmaf(ddA, full, bj), 0.f) * wj;
#pragma unroll
        for (int off = 32; off > 0; off >>= 1) pA += __shfl_down(pA, off);
        if (j == 0) zg[dA] = pA * ddA;

        if (hasB) {
            prow[0] = make_float4(aB[0], aB[1], aB[2], aB[3]);
            prow[1] = make_float4(aB[4], aB[5], aB[6], aB[7]);
            float fullB = 0.f;
#pragma unroll
            for (int g = 0; g < 8; ++g) fullB += sVp[r][g][j];
            float pB = fmaxf(fmaf(ddB, fullB, bj), 0.f) * wj;
#pragma unroll
            for (int off = 32; off > 0; off >>= 1) pB += __shfl_down(pB, off);
            if (j == 0) zg[dB] = pB * ddB;
        }
    }
}

// out[d] = dd*(zg[d] + sum zg[s]) + b_out.  One wave per node, lane = edge slot.
__global__ __launch_bounds__(TPB) void k_out(
    const float* __restrict__ zg, const float* __restrict__ dinv,
    const int* __restrict__ row_start, const unsigned short* __restrict__ bucket,
    const float* __restrict__ b_out, float* __restrict__ out, int n, int E) {
    int t = blockIdx.x * blockDim.x + threadIdx.x;
    int d = t >> 6, lane = t & 63;
    if (d >= n) return;
    int k0 = row_start[d], k1 = row_start[d + 1];
    k1 = min(k1, E); k0 = max(min(k0, k1), 0);
    unsigned nm1 = (unsigned)(n - 1);
    float v = 0.f;
    for (int k = k0 + lane; k < k1; k += 64) {
        unsigned s = min((unsigned)bucket[k], nm1);
        v += zg[s];
    }
#pragma unroll
    for (int off = 32; off > 0; off >>= 1) v += __shfl_down(v, off);
    if (lane == 0) out[d] = fmaf(zg[d] + v, dinv[d], b_out[0]);
}

extern "C" void kernel_launch(void* const* d_in, const int* in_sizes, int n_in,
                              void* d_out, int out_size, void* d_ws, size_t ws_size,
                              hipStream_t stream) {
    const float* x     = (const float*)d_in[0];
    const int*   ei    = (const int*)d_in[1];
    const float* W_in  = (const float*)d_in[2];
    const float* b_in  = (const float*)d_in[3];
    const float* W_h   = (const float*)d_in[4];
    const float* b_h   = (const float*)d_in[5];
    const float* W_out = (const float*)d_in[6];
    const float* b_out = (const float*)d_in[7];
    float* out = (float*)d_out;

    int N = in_sizes[0] / 4;
    int E = in_sizes[1] / 2;
    const int* src = ei;
    const int* dst = ei + E;

    char* ws = (char*)d_ws;
    bf16* gA               = (bf16*)ws;           ws += (size_t)N * 64 * 2;
    bf16* gB               = (bf16*)ws;           ws += (size_t)N * 64 * 2;
    float4* xt             = (float4*)ws;         ws += (size_t)N * 16;
    unsigned short* bucket = (unsigned short*)ws; ws += (size_t)E * 2;
    unsigned* staging      = (unsigned*)ws;       ws += (size_t)E * 4;
    int*  row_start        = (int*)ws;            ws += (size_t)(N + 1) * 4;
    float* dinv            = (float*)ws;          ws += (size_t)N * 4;
    float* zg              = (float*)ws;          ws += (size_t)N * 4;
    int*  bktcnt           = (int*)ws;            ws += 256 * 4;
    int*  ticket           = (int*)ws;            ws += 4;
    int*  bktbase          = (int*)ws;            ws += 257 * 4;
    int*  bcur             = (int*)ws;            // 256 ints

    int B     = (N + 255) >> 8;          // dst buckets (196 for N=50000; <=256)
    int gN4   = (N + 3) / 4;             // 4 nodes/block (1 wave per node)
    int gPers = 1024;                    // persistent conv grid (4 blocks/CU)
    int gBin  = (E + CHUNK - 1) / CHUNK; // 391

    // ---- CSR build + norms (bucket-centric; scan fused into count) ----
    k_zero_b<<<1, 256, 0, stream>>>(bktcnt, ticket);
    k_bktcnt<<<gBin, TPB, 0, stream>>>(dst, bktcnt, ticket, bktbase, bcur, E, N);
    k_bin<<<gBin, TPB, 0, stream>>>(src, dst, bcur, staging, E, N);
    k_unbin2<<<B, TPB, 0, stream>>>(staging, bktbase, x, xt, row_start, dinv, bucket, E, N);

    // ---- layers (feature buffers premultiplied by dinv) ----
    k_gconv1<<<gPers, TPB, 0, stream>>>(xt, dinv, row_start, bucket, W_in, b_in, W_h, gB, N, E);
    k_gconv<<<gPers, TPB, 0, stream>>>(gB, dinv, row_start, bucket, b_h, W_h + 4096, gA, N, E);
    k_gconv<<<gPers, TPB, 0, stream>>>(gA, dinv, row_start, bucket, b_h + 64, W_h + 8192, gB, N, E);
    k_gconv_z<<<gPers, TPB, 0, stream>>>(gB, dinv, row_start, bucket, b_h + 128, W_out, zg, N, E);
    k_out<<<gN4, TPB, 0, stream>>>(zg, dinv, row_start, bucket, b_out, out, N, E);
}

// Round 6
// 259.285 us; speedup vs baseline: 1.5932x; 1.5932x over previous
//
#include <hip/hip_runtime.h>
#include <hip/hip_bf16.h>

// GCN: N=50000, E=800000, hidden 64, 5 convs (relu on first 4).
// f32 tensors, int32 edge_index, f32 d_out[N].  ws_size in [19.8, 26.0) MB.
// r23: r22 post-mortem — dual-node gather spilled (VGPR report 64, WRITE_SIZE 84MB
// = scratch). Revert to r21 base; this round pipelines the per-node ADDRESS chain
// instead (cheap in registers): at node-loop top issue next node's row_start/dinv;
// after the current gather issue next node's FIRST bucket chunk; rotate. Removes
// ~600cy of the ~2000cy per-node chain at ~+8 VGPR (est ~118 < 128 cap, no spill).
// Applied to k_gconv (x2) and k_gconv_z (now persistent, same shape, no wreg).
// gconv1 / k_out / CSR unchanged from r21.
// Workspace (~19.0 MB): gA bf16[N*64] | gB bf16[N*64] | xt f32x4[N] | bucket u16[E]
//   | staging u32[E] | row_start i32[N+1] | dinv f32[N] | zg f32[N] | bktcnt i32[256]
//   | ticket i32 | bktbase i32[257] | bcur i32[256]

#define TPB 256
#define EPT 8                    // edges per thread in k_bktcnt / k_bin
#define CHUNK (TPB * EPT)        // 2048 edges per block
typedef __hip_bfloat16 bf16;
#define B2F __bfloat162float

__global__ void k_zero_b(int* __restrict__ bktcnt, int* __restrict__ ticket) {
    bktcnt[threadIdx.x] = 0;
    if (threadIdx.x == 0) *ticket = 0;
}

// Per-bucket (dst>>8) edge counts via LDS histogram; LAST block (ticket) also
// performs the 256-wide exclusive scan -> bktbase[257], bcur (fuses k_bktscan).
__global__ __launch_bounds__(TPB) void k_bktcnt(
    const int* __restrict__ dst, int* __restrict__ bktcnt, int* __restrict__ ticket,
    int* __restrict__ bktbase, int* __restrict__ bcur, int E, int n) {
    __shared__ int h[256];
    __shared__ int lastFlag;
    int tid = threadIdx.x;
    h[tid] = 0;
    __syncthreads();
    int e0 = blockIdx.x * CHUNK;
#pragma unroll
    for (int u = 0; u < EPT; ++u) {
        int e = e0 + u * TPB + tid;
        if (e < E) {
            int d = dst[e];
            if ((unsigned)d < (unsigned)n) atomicAdd(&h[d >> 8], 1);
        }
    }
    __syncthreads();
    if (h[tid]) atomicAdd(&bktcnt[tid], h[tid]);
    __threadfence();                               // counts visible before ticket
    __syncthreads();
    if (tid == 0) lastFlag = (atomicAdd(ticket, 1) == (int)gridDim.x - 1);
    __syncthreads();
    if (!lastFlag) return;                         // block-uniform exit
    // last block: coherent read of final counts, then scan (reuse h as buffer)
    int v = atomicAdd(&bktcnt[tid], 0);
    h[tid] = v;
    __syncthreads();
    for (int off = 1; off < 256; off <<= 1) {
        int u2 = (tid >= off) ? h[tid - off] : 0;
        __syncthreads();
        h[tid] += u2;
        __syncthreads();
    }
    int excl = h[tid] - v;
    bktbase[tid] = excl;
    bcur[tid] = excl;
    if (tid == 255) bktbase[256] = h[tid];
}

// Pass 1: bin edges by dst>>8 into staging (record = src | (dst&255)<<16).
__global__ __launch_bounds__(TPB) void k_bin(
    const int* __restrict__ src, const int* __restrict__ dst,
    int* __restrict__ bcur, unsigned* __restrict__ staging, int E, int n) {
    __shared__ int hcnt[256];
    __shared__ int hbase[256];
    int tid = threadIdx.x;
    int e0 = blockIdx.x * CHUNK;
    hcnt[tid] = 0;
    __syncthreads();

    int eb[EPT];
    unsigned rec[EPT];
#pragma unroll
    for (int u = 0; u < EPT; ++u) {
        int e = e0 + u * TPB + tid;
        eb[u] = -1;
        if (e < E) {
            int d = dst[e], s = src[e];
            if ((unsigned)d < (unsigned)n && (unsigned)s < (unsigned)n) {
                eb[u] = d >> 8;
                rec[u] = (unsigned)s | ((unsigned)(d & 255) << 16);
                atomicAdd(&hcnt[eb[u]], 1);
            }
        }
    }
    __syncthreads();
    int c = hcnt[tid];
    hbase[tid] = (c > 0) ? atomicAdd(&bcur[tid], c) : 0;
    hcnt[tid] = 0;
    __syncthreads();
#pragma unroll
    for (int u = 0; u < EPT; ++u) {
        if (eb[u] >= 0) {
            int r = atomicAdd(&hcnt[eb[u]], 1);
            int pos = hbase[eb[u]] + r;
            if ((unsigned)pos < (unsigned)E) staging[pos] = rec[u];  // replay-safe
        }
    }
}

// Pass 2: one block per bucket. Per-node histogram + prefix in LDS -> row_start,
// dinv, xt (=x*dinv), and record placement via LDS cursors.
__global__ __launch_bounds__(TPB) void k_unbin2(
    const unsigned* __restrict__ staging, const int* __restrict__ bktbase,
    const float* __restrict__ x, float4* __restrict__ xt,
    int* __restrict__ row_start, float* __restrict__ dinv,
    unsigned short* __restrict__ bucket, int E, int n) {
    __shared__ int cnt[256];
    __shared__ int scn[256];
    __shared__ int cur[256];
    int b = blockIdx.x, tid = threadIdx.x;
    int lo = bktbase[b], hi = bktbase[b + 1];
    lo = max(0, min(lo, E)); hi = max(lo, min(hi, E));

    cnt[tid] = 0;
    __syncthreads();
    for (int i = lo + tid; i < hi; i += TPB)
        atomicAdd(&cnt[(staging[i] >> 16) & 255], 1);
    __syncthreads();

    int v = cnt[tid];
    scn[tid] = v;
    __syncthreads();
    for (int off = 1; off < 256; off <<= 1) {
        int u = (tid >= off) ? scn[tid - off] : 0;
        __syncthreads();
        scn[tid] += u;
        __syncthreads();
    }
    int excl = scn[tid] - v;
    int base = min(lo + excl, E);
    cur[tid] = base;
    int d = (b << 8) + tid;
    if (d < n) {
        row_start[d] = base;
        float di = rsqrtf((float)v + 1.0f);    // +1 self-loop
        dinv[d] = di;
        float4 xv = ((const float4*)x)[d];     // x is f32[N][4], 16B aligned
        xv.x *= di; xv.y *= di; xv.z *= di; xv.w *= di;
        xt[d] = xv;                            // premultiplied raw features
        if (d == n - 1) row_start[n] = min(base + v, E);
    }
    __syncthreads();

    for (int i = lo + tid; i < hi; i += TPB) {
        unsigned r = staging[i];
        int t = (r >> 16) & 255;
        int pos = atomicAdd(&cur[t], 1);
        if ((unsigned)pos < (unsigned)E) bucket[pos] = (unsigned short)(r & 0xffffu);
    }
}

__device__ __forceinline__ void acc_oct(float* a, uint4 w) {
    a[0] += __uint_as_float(w.x << 16);
    a[1] += __uint_as_float(w.x & 0xffff0000u);
    a[2] += __uint_as_float(w.y << 16);
    a[3] += __uint_as_float(w.y & 0xffff0000u);
    a[4] += __uint_as_float(w.z << 16);
    a[5] += __uint_as_float(w.z & 0xffff0000u);
    a[6] += __uint_as_float(w.w << 16);
    a[7] += __uint_as_float(w.w & 0xffff0000u);
}

// OCT gather with pre-loaded FIRST bucket chunk (rec0): 8 edges per load instr.
// Lane group grp=lane>>3 takes edge k+grp; lane i=lane&7 loads uint4 = 8 packed
// bf16 feats (8 lanes x 16B = full 128B row). Partials in registers; caller
// combines across groups via padded LDS rows.
__device__ __forceinline__ void agg_oct_pf(const bf16* __restrict__ g,
                                           const unsigned short* __restrict__ bucket,
                                           int k0, int k1, int d, float* __restrict__ a,
                                           int lane, unsigned nm1, unsigned Em1,
                                           int rec0) {
    int grp = lane >> 3, i = lane & 7;
#pragma unroll
    for (int m = 0; m < 8; ++m) a[m] = 0.f;
    if (grp == 0) {  // self term
        uint4 w = *(const uint4*)(g + (size_t)d * 64 + 8 * i);
        acc_oct(a, w);
    }
    bool first = true;
    for (int base = k0; base < k1; base += 64) {
        int cnt = min(64, k1 - base);
        int rec = first ? rec0 : (int)bucket[min((unsigned)(base + lane), Em1)];
        first = false;
        int k = 0;
        for (; k + 16 <= cnt; k += 16) {                      // 16 edges, 2 oct loads
            unsigned s0 = min((unsigned)__shfl(rec, k + grp), nm1);
            unsigned s1 = min((unsigned)__shfl(rec, k + 8 + grp), nm1);
            uint4 w0 = *(const uint4*)(g + (size_t)s0 * 64 + 8 * i);
            uint4 w1 = *(const uint4*)(g + (size_t)s1 * 64 + 8 * i);
            acc_oct(a, w0);
            acc_oct(a, w1);
        }
        for (; k < cnt; k += 8) {                             // tail, predicated
            int e = k + grp;
            unsigned s = min((unsigned)__shfl(rec, min(e, 63)), nm1);
            uint4 w = *(const uint4*)(g + (size_t)s * 64 + 8 * i);
            if (e < cnt) acc_oct(a, w);
        }
    }
}

// Layer 1, aggregate-first (r21, unchanged): agg4[d] = xt[d] + sum xt[s].
__global__ __launch_bounds__(TPB, 4) void k_gconv1(
    const float4* __restrict__ xt, const float* __restrict__ dinv,
    const int* __restrict__ row_start, const unsigned short* __restrict__ bucket,
    const float* __restrict__ W_in, const float* __restrict__ b_in,
    const float* __restrict__ Wh0, bf16* __restrict__ gOut, int n, int E) {
    __shared__ float sAct[4][64];
    int tid = threadIdx.x;
    int r = tid >> 6, j = tid & 63;
    unsigned nm1 = (unsigned)(n - 1);

    float wreg[64];
#pragma unroll
    for (int k = 0; k < 64; ++k) wreg[k] = Wh0[k * 64 + j];
    float win0 = W_in[0 * 64 + j], win1 = W_in[1 * 64 + j];
    float win2 = W_in[2 * 64 + j], win3 = W_in[3 * 64 + j];
    float bj = b_in[j];

    int nw = gridDim.x * 4;
    for (int d = blockIdx.x * 4 + r; d < n; d += nw) {      // wave-uniform loop
        float dd = dinv[d];
        int k0 = row_start[d], k1 = row_start[d + 1];
        k1 = min(k1, E); k0 = max(min(k0, k1), 0);

        float4 v = make_float4(0.f, 0.f, 0.f, 0.f);
        if (j == 0) v = xt[d];                              // self term
        for (int k = k0 + j; k < k1; k += 64) {
            unsigned s = min((unsigned)bucket[k], nm1);
            float4 t = xt[s];
            v.x += t.x; v.y += t.y; v.z += t.z; v.w += t.w;
        }
#pragma unroll
        for (int off = 1; off < 64; off <<= 1) {            // butterfly: all lanes
            v.x += __shfl_xor(v.x, off);
            v.y += __shfl_xor(v.y, off);
            v.z += __shfl_xor(v.z, off);
            v.w += __shfl_xor(v.w, off);
        }
        float dot = fmaf(v.x, win0, fmaf(v.y, win1, fmaf(v.z, win2, v.w * win3)));
        float act = fmaxf(fmaf(dd, dot, bj), 0.f);
        sAct[r][j] = act;                 // wave-local RAW -> lgkmcnt, no barrier

        float acc0 = 0.f, acc1 = 0.f, acc2 = 0.f, acc3 = 0.f;
        const float4* ap = (const float4*)&sAct[r][0];
#pragma unroll
        for (int k4 = 0; k4 < 16; ++k4) {
            float4 av = ap[k4];           // wave-uniform address -> broadcast b128
            acc0 = fmaf(av.x, wreg[4 * k4 + 0], acc0);
            acc1 = fmaf(av.y, wreg[4 * k4 + 1], acc1);
            acc2 = fmaf(av.z, wreg[4 * k4 + 2], acc2);
            acc3 = fmaf(av.w, wreg[4 * k4 + 3], acc3);
        }
        float acc = (acc0 + acc1) + (acc2 + acc3);
        gOut[(size_t)d * 64 + j] = __float2bfloat16(acc * dd);
    }
}

// Persistent fused middle layer with ADDRESS-CHAIN pipelining: at loop top issue
// next node's row_start/dinv; after the current gather issue next node's first
// bucket chunk; rotate at loop end. Gather/combine/transform identical to r21.
__global__ __launch_bounds__(TPB, 4) void k_gconv(
    const bf16* __restrict__ gIn, const float* __restrict__ dinv,
    const int* __restrict__ row_start, const unsigned short* __restrict__ bucket,
    const float* __restrict__ bias, const float* __restrict__ W,
    bf16* __restrict__ gOut, int n, int E) {
    __shared__ float sVp[4][8][68];      // 8704 B, padded
    int tid = threadIdx.x;
    int r = tid >> 6, j = tid & 63;
    int grp = j >> 3, i = j & 7;
    unsigned nm1 = (unsigned)(n - 1), Em1 = (unsigned)(E - 1);

    float wreg[64];
#pragma unroll
    for (int k = 0; k < 64; ++k) wreg[k] = W[k * 64 + j];   // coalesced per k
    float bj = bias[j];

    int nw = gridDim.x * 4;
    int d0 = blockIdx.x * 4 + r;
    // prologue: meta + first bucket chunk of the first node
    float dd = 0.f; int k0 = 0, k1 = 0, rec0 = 0;
    if (d0 < n) {
        dd = dinv[d0];
        k1 = min(row_start[d0 + 1], E);
        k0 = max(min(row_start[d0], k1), 0);
        rec0 = bucket[min((unsigned)(k0 + j), Em1)];
    }
    for (int d = d0; d < n; d += nw) {                      // wave-uniform loop
        // issue next node's meta loads (overlap with this node's gather)
        int dn = d + nw;
        float ddn = 0.f; int k0n = 0, k1n = 0;
        if (dn < n) {                                       // wave-uniform branch
            ddn = dinv[dn];
            k0n = row_start[dn];
            k1n = row_start[dn + 1];
        }

        float a[8];
        agg_oct_pf(gIn, bucket, k0, k1, d, a, j, nm1, Em1, rec0);

        // next node's first bucket chunk (k0n arrived during the gather);
        // the combine+transform below covers its latency
        int k1nc = min(k1n, E);
        int k0nc = max(min(k0n, k1nc), 0);
        int rec0n = bucket[min((unsigned)(k0nc + j), Em1)];

        // partials -> padded LDS rows (wave-local, in-order DS => no barrier)
        float4* prow = (float4*)&sVp[r][grp][8 * i];
        prow[0] = make_float4(a[0], a[1], a[2], a[3]);
        prow[1] = make_float4(a[4], a[5], a[6], a[7]);
        float full = 0.f;
#pragma unroll
        for (int g = 0; g < 8; ++g) full += sVp[r][g][j];   // 2-way bank: free

        float act = fmaxf(fmaf(dd, full, bj), 0.f);
        sVp[r][0][j] = act;               // reads above already issued (in-order)

        float acc0 = 0.f, acc1 = 0.f, acc2 = 0.f, acc3 = 0.f;
#pragma unroll
        for (int k4 = 0; k4 < 16; ++k4) {
            float4 av = *(const float4*)&sVp[r][0][4 * k4];   // broadcast b128
            acc0 = fmaf(av.x, wreg[4 * k4 + 0], acc0);
            acc1 = fmaf(av.y, wreg[4 * k4 + 1], acc1);
            acc2 = fmaf(av.z, wreg[4 * k4 + 2], acc2);
            acc3 = fmaf(av.w, wreg[4 * k4 + 3], acc3);
        }
        float acc = (acc0 + acc1) + (acc2 + acc3);
        gOut[(size_t)d * 64 + j] = __float2bfloat16(acc * dd);

        // rotate pipeline registers
        dd = ddn; k0 = k0nc; k1 = k1nc; rec0 = rec0n;
    }
}

// Last hidden conv fused with 64->1 matmul, persistent + address pipelining:
// zg[d] = (relu(dd*sum+b) . Wout) * dd.  Same gather shape, light tail, no wreg.
__global__ __launch_bounds__(TPB, 4) void k_gconv_z(
    const bf16* __restrict__ gIn, const float* __restrict__ dinv,
    const int* __restrict__ row_start, const unsigned short* __restrict__ bucket,
    const float* __restrict__ bias, const float* __restrict__ Wout,
    float* __restrict__ zg, int n, int E) {
    __shared__ float sVp[4][8][68];
    int tid = threadIdx.x;
    int r = tid >> 6, j = tid & 63;
    int grp = j >> 3, i = j & 7;
    unsigned nm1 = (unsigned)(n - 1), Em1 = (unsigned)(E - 1);
    float bj = bias[j], wj = Wout[j];

    int nw = gridDim.x * 4;
    int d0 = blockIdx.x * 4 + r;
    float dd = 0.f; int k0 = 0, k1 = 0, rec0 = 0;
    if (d0 < n) {
        dd = dinv[d0];
        k1 = min(row_start[d0 + 1], E);
        k0 = max(min(row_start[d0], k1), 0);
        rec0 = bucket[min((unsigned)(k0 + j), Em1)];
    }
    for (int d = d0; d < n; d += nw) {                      // wave-uniform loop
        int dn = d + nw;
        float ddn = 0.f; int k0n = 0, k1n = 0;
        if (dn < n) {
            ddn = dinv[dn];
            k0n = row_start[dn];
            k1n = row_start[dn + 1];
        }

        float a[8];
        agg_oct_pf(gIn, bucket, k0, k1, d, a, j, nm1, Em1, rec0);

        int k1nc = min(k1n, E);
        int k0nc = max(min(k0n, k1nc), 0);
        int rec0n = bucket[min((unsigned)(k0nc + j), Em1)];

        float4* prow = (float4*)&sVp[r][grp][8 * i];
        prow[0] = make_float4(a[0], a[1], a[2], a[3]);
        prow[1] = make_float4(a[4], a[5], a[6], a[7]);
        float full = 0.f;
#pragma unroll
        for (int g = 0; g < 8; ++g) full += sVp[r][g][j];

        float p = fmaxf(fmaf(dd, full, bj), 0.f) * wj;
#pragma unroll
        for (int off = 32; off > 0; off >>= 1) p += __shfl_down(p, off);
        if (j == 0) zg[d] = p * dd;

        dd = ddn; k0 = k0nc; k1 = k1nc; rec0 = rec0n;
    }
}

// out[d] = dd*(zg[d] + sum zg[s]) + b_out.  One wave per node, lane = edge slot.
__global__ __launch_bounds__(TPB) void k_out(
    const float* __restrict__ zg, const float* __restrict__ dinv,
    const int* __restrict__ row_start, const unsigned short* __restrict__ bucket,
    const float* __restrict__ b_out, float* __restrict__ out, int n, int E) {
    int t = blockIdx.x * blockDim.x + threadIdx.x;
    int d = t >> 6, lane = t & 63;
    if (d >= n) return;
    int k0 = row_start[d], k1 = row_start[d + 1];
    k1 = min(k1, E); k0 = max(min(k0, k1), 0);
    unsigned nm1 = (unsigned)(n - 1);
    float v = 0.f;
    for (int k = k0 + lane; k < k1; k += 64) {
        unsigned s = min((unsigned)bucket[k], nm1);
        v += zg[s];
    }
#pragma unroll
    for (int off = 32; off > 0; off >>= 1) v += __shfl_down(v, off);
    if (lane == 0) out[d] = fmaf(zg[d] + v, dinv[d], b_out[0]);
}

extern "C" void kernel_launch(void* const* d_in, const int* in_sizes, int n_in,
                              void* d_out, int out_size, void* d_ws, size_t ws_size,
                              hipStream_t stream) {
    const float* x     = (const float*)d_in[0];
    const int*   ei    = (const int*)d_in[1];
    const float* W_in  = (const float*)d_in[2];
    const float* b_in  = (const float*)d_in[3];
    const float* W_h   = (const float*)d_in[4];
    const float* b_h   = (const float*)d_in[5];
    const float* W_out = (const float*)d_in[6];
    const float* b_out = (const float*)d_in[7];
    float* out = (float*)d_out;

    int N = in_sizes[0] / 4;
    int E = in_sizes[1] / 2;
    const int* src = ei;
    const int* dst = ei + E;

    char* ws = (char*)d_ws;
    bf16* gA               = (bf16*)ws;           ws += (size_t)N * 64 * 2;
    bf16* gB               = (bf16*)ws;           ws += (size_t)N * 64 * 2;
    float4* xt             = (float4*)ws;         ws += (size_t)N * 16;
    unsigned short* bucket = (unsigned short*)ws; ws += (size_t)E * 2;
    unsigned* staging      = (unsigned*)ws;       ws += (size_t)E * 4;
    int*  row_start        = (int*)ws;            ws += (size_t)(N + 1) * 4;
    float* dinv            = (float*)ws;          ws += (size_t)N * 4;
    float* zg              = (float*)ws;          ws += (size_t)N * 4;
    int*  bktcnt           = (int*)ws;            ws += 256 * 4;
    int*  ticket           = (int*)ws;            ws += 4;
    int*  bktbase          = (int*)ws;            ws += 257 * 4;
    int*  bcur             = (int*)ws;            // 256 ints

    int B     = (N + 255) >> 8;          // dst buckets (196 for N=50000; <=256)
    int gN4   = (N + 3) / 4;             // 4 nodes/block (1 wave per node)
    int gPers = 1024;                    // persistent conv grid (4 blocks/CU)
    int gBin  = (E + CHUNK - 1) / CHUNK; // 391

    // ---- CSR build + norms (bucket-centric; scan fused into count) ----
    k_zero_b<<<1, 256, 0, stream>>>(bktcnt, ticket);
    k_bktcnt<<<gBin, TPB, 0, stream>>>(dst, bktcnt, ticket, bktbase, bcur, E, N);
    k_bin<<<gBin, TPB, 0, stream>>>(src, dst, bcur, staging, E, N);
    k_unbin2<<<B, TPB, 0, stream>>>(staging, bktbase, x, xt, row_start, dinv, bucket, E, N);

    // ---- layers (feature buffers premultiplied by dinv) ----
    k_gconv1<<<gPers, TPB, 0, stream>>>(xt, dinv, row_start, bucket, W_in, b_in, W_h, gB, N, E);
    k_gconv<<<gPers, TPB, 0, stream>>>(gB, dinv, row_start, bucket, b_h, W_h + 4096, gA, N, E);
    k_gconv<<<gPers, TPB, 0, stream>>>(gA, dinv, row_start, bucket, b_h + 64, W_h + 8192, gB, N, E);
    k_gconv_z<<<gPers, TPB, 0, stream>>>(gB, dinv, row_start, bucket, b_h + 128, W_out, zg, N, E);
    k_out<<<gN4, TPB, 0, stream>>>(zg, dinv, row_start, bucket, b_out, out, N, E);
}